// Round 6
// baseline (148.479 us; speedup 1.0000x reference)
//
#include <hip/hip_runtime.h>
#include <hip/hip_bf16.h>
#include <stdint.h>

#define B_DIM 8
#define C_DIM 512
#define N_DIM 3136
#define NP    3200   // N padded to 25*128
#define BK    32
#define NT    25     // NP/128
#define NTRI  (NT * (NT + 1) / 2)  // 325 lower-tri block tiles

typedef short bf16x8 __attribute__((ext_vector_type(8)));
typedef float f32x4  __attribute__((ext_vector_type(4)));

__device__ __forceinline__ void gload16(const void* g, void* l) {
  __builtin_amdgcn_global_load_lds(
      (const __attribute__((address_space(1))) void*)g,
      (__attribute__((address_space(3))) void*)l, 16, 0, 0);
}

__device__ __forceinline__ float bf2f(ushort u) {
  union { uint32_t i; float f; } c;
  c.i = ((uint32_t)u) << 16;
  return c.f;
}

__device__ __forceinline__ ushort f2bf(float f) {
  __hip_bfloat16 h = __float2bfloat16(f);
  return *(ushort*)&h;
}

// x[b][c][n] f32 -> kt[b][n][c] bf16 (n padded to NP, pad rows zero).
__global__ __launch_bounds__(256) void k_transpose(const float* __restrict__ x,
                                                   ushort* __restrict__ kt) {
  __shared__ float tile[64][33];  // [c_local][n_local]
  const int b  = blockIdx.z;
  const int n0 = blockIdx.x * 32;
  const int c0 = blockIdx.y * 64;
  const int tx = threadIdx.x;  // 32 (n)
  const int ty = threadIdx.y;  // 8  (c)
#pragma unroll
  for (int j = 0; j < 8; ++j) {
    int c = c0 + ty + 8 * j;
    int n = n0 + tx;
    float v = (n < N_DIM) ? x[((size_t)b * C_DIM + c) * N_DIM + n] : 0.0f;
    tile[ty + 8 * j][tx] = v;
  }
  __syncthreads();
  const int tid = ty * 32 + tx;
  const int r = tid >> 5;   // n-sub 0..7
  const int p = tid & 31;   // c-pair 0..31
#pragma unroll
  for (int i = 0; i < 4; ++i) {
    int nl = r + 8 * i;
    int n = n0 + nl;
    uint32_t u = (uint32_t)f2bf(tile[2 * p][nl]) |
                 ((uint32_t)f2bf(tile[2 * p + 1][nl]) << 16);
    *(uint32_t*)(kt + ((size_t)b * NP + n) * C_DIM + c0 + 2 * p) = u;
  }
}

// sq[b*NP+n] = sum_c kt[b][n][c]^2 (fp32 accum over bf16 values).
__global__ __launch_bounds__(256) void k_norms(const ushort* __restrict__ kt,
                                               float* __restrict__ sq) {
  const int row  = blockIdx.x * 4 + (threadIdx.x >> 6);
  const int lane = threadIdx.x & 63;
  const ushort* p = kt + (size_t)row * C_DIM + lane * 8;
  bf16x8 v = *(const bf16x8*)p;
  float s = 0.0f;
#pragma unroll
  for (int j = 0; j < 8; ++j) {
    float f = bf2f((ushort)v[j]);
    s += f * f;
  }
#pragma unroll
  for (int m = 32; m >= 1; m >>= 1) s += __shfl_xor(s, m);
  if (lane == 0) sq[row] = s;
}

// Symmetric GEMM, lower-tri tiles. R3-proven main loop (single-buffer,
// 2 barriers/K-step). Epilogue: direct scalar stores (4x64B segments/instr)
// + BARRIER-FREE mirror via per-fragment f32x4 transposed stores: in
// out[col][row], the 4 consecutive r of acc[mi][ni] are 4 consecutive
// addresses, 16B-aligned. No LDS round-trip (R4 measured that at ~+11us).
__global__ __launch_bounds__(256) void k_gemm(const ushort* __restrict__ kt,
                                              const float* __restrict__ sq,
                                              float* __restrict__ out) {
  __shared__ __attribute__((aligned(16))) char smem[32768];
  ushort* tA = (ushort*)smem;            // [128][32] bf16, 8 KB
  ushort* tB = (ushort*)(smem + 8192);   // [128][32] bf16, 8 KB

  const int id = blockIdx.x;
  const int b = id & 7;        // batch -> XCD round-robin
  const int t = id >> 3;       // triangular tile index 0..324
  int bx = (int)((sqrtf(8.0f * (float)t + 1.0f) - 1.0f) * 0.5f);
  while ((bx + 1) * (bx + 2) / 2 <= t) ++bx;
  while (bx * (bx + 1) / 2 > t) --bx;
  const int by = t - bx * (bx + 1) / 2;

  const int n0 = bx * 128;  // rows (A tile)
  const int m0 = by * 128;  // cols (B tile)
  const int tid  = threadIdx.x;
  const int wave = tid >> 6;
  const int lane = tid & 63;
  const ushort* ktb = kt + (size_t)b * NP * C_DIM;

  const int wr = (wave >> 1) * 64;
  const int wc = (wave & 1) * 64;
  const int koff = lane >> 4;
  const int rl = lane & 15;

  f32x4 acc[4][4];
#pragma unroll
  for (int mi = 0; mi < 4; ++mi)
#pragma unroll
    for (int ni = 0; ni < 4; ++ni)
      acc[mi][ni] = (f32x4){0.f, 0.f, 0.f, 0.f};

  for (int ks = 0; ks < C_DIM / BK; ++ks) {
    __syncthreads();
    const int kbase = ks * BK;
#pragma unroll
    for (int i = 0; i < 2; ++i) {
      int q   = i * 256 + wave * 64 + lane;   // 16B chunk index 0..511
      int row = q >> 2;
      int lk  = (q & 3) ^ ((q >> 3) & 3);     // pre-swizzled global source
      const ushort* gA = ktb + (size_t)(n0 + row) * C_DIM + kbase + lk * 8;
      const ushort* gB = ktb + (size_t)(m0 + row) * C_DIM + kbase + lk * 8;
      char* lA = (char*)tA + (i * 256 + wave * 64) * 16;  // wave-uniform base
      char* lB = (char*)tB + (i * 256 + wave * 64) * 16;
      gload16(gA, lA);
      gload16(gB, lB);
    }
    __syncthreads();

    bf16x8 aF[4], bF[4];
#pragma unroll
    for (int mi = 0; mi < 4; ++mi) {
      int row  = wr + mi * 16 + rl;
      int phys = koff ^ ((row >> 1) & 3);
      aF[mi] = *(const bf16x8*)((const char*)tA + row * 64 + phys * 16);
    }
#pragma unroll
    for (int ni = 0; ni < 4; ++ni) {
      int row  = wc + ni * 16 + rl;
      int phys = koff ^ ((row >> 1) & 3);
      bF[ni] = *(const bf16x8*)((const char*)tB + row * 64 + phys * 16);
    }
#pragma unroll
    for (int mi = 0; mi < 4; ++mi)
#pragma unroll
      for (int ni = 0; ni < 4; ++ni)
        acc[mi][ni] = __builtin_amdgcn_mfma_f32_16x16x32_bf16(
            aF[mi], bF[ni], acc[mi][ni], 0, 0, 0);
  }

  // ---- epilogue: normalize ----
  const float* sqb = sq + b * NP;
  float rrow[4][4], rcol[4];
#pragma unroll
  for (int mi = 0; mi < 4; ++mi)
#pragma unroll
    for (int r = 0; r < 4; ++r) {
      float s = sqb[n0 + wr + mi * 16 + koff * 4 + r];
      rrow[mi][r] = 1.0f / fmaxf(sqrtf(s), 1e-8f);
    }
#pragma unroll
  for (int ni = 0; ni < 4; ++ni) {
    float s = sqb[m0 + wc + ni * 16 + rl];
    rcol[ni] = 1.0f / fmaxf(sqrtf(s), 1e-8f);
  }
#pragma unroll
  for (int mi = 0; mi < 4; ++mi)
#pragma unroll
    for (int ni = 0; ni < 4; ++ni)
#pragma unroll
      for (int r = 0; r < 4; ++r)
        acc[mi][ni][r] *= rrow[mi][r] * rcol[ni];

  float* outb = out + (size_t)b * N_DIM * N_DIM;

  // direct write: out[n0+row][m0+col] — 4x64B segments per wave-store
#pragma unroll
  for (int mi = 0; mi < 4; ++mi) {
#pragma unroll
    for (int ni = 0; ni < 4; ++ni) {
#pragma unroll
      for (int r = 0; r < 4; ++r) {
        int row = n0 + wr + mi * 16 + koff * 4 + r;
        int col = m0 + wc + ni * 16 + rl;
        if (row < N_DIM && col < N_DIM)
          outb[(size_t)row * N_DIM + col] = acc[mi][ni][r];
      }
    }
  }

  // mirror write: out[col][row_base..row_base+3] = acc[mi][ni] as one f32x4.
  // row_base = n0+wr+mi*16+koff*4 is 16B-aligned; N_DIM%16==0 so the 4-chunk
  // is either fully valid or fully pad. No LDS, no barriers.
  if (bx != by) {
#pragma unroll
    for (int mi = 0; mi < 4; ++mi) {
      int row_base = n0 + wr + mi * 16 + koff * 4;
      if (row_base < N_DIM) {
#pragma unroll
        for (int ni = 0; ni < 4; ++ni) {
          int col = m0 + wc + ni * 16 + rl;
          if (col < N_DIM)
            *(f32x4*)(outb + (size_t)col * N_DIM + row_base) = acc[mi][ni];
        }
      }
    }
  }
}

extern "C" void kernel_launch(void* const* d_in, const int* in_sizes, int n_in,
                              void* d_out, int out_size, void* d_ws, size_t ws_size,
                              hipStream_t stream) {
  const float* x = (const float*)d_in[0];
  float* out = (float*)d_out;

  ushort* kt = (ushort*)d_ws;
  float* sq = (float*)((char*)d_ws + (size_t)B_DIM * NP * C_DIM * 2);

  dim3 gT(NP / 32, C_DIM / 64, B_DIM);  // 100,8,8
  k_transpose<<<gT, dim3(32, 8), 0, stream>>>(x, kt);

  k_norms<<<B_DIM * NP / 4, 256, 0, stream>>>(kt, sq);

  k_gemm<<<NTRI * B_DIM, 256, 0, stream>>>(kt, sq, out);  // 2600 blocks
}

// Round 7
// 134.724 us; speedup vs baseline: 1.1021x; 1.1021x over previous
//
#include <hip/hip_runtime.h>
#include <hip/hip_bf16.h>
#include <stdint.h>

#define B_DIM 8
#define C_DIM 512
#define N_DIM 3136
#define NP    3200               // kt rows (25*128); rows 3136..3199 are zero
#define BM    256
#define BK    64
#define NKT   (C_DIM / BK)       // 8 K-tiles
#define NT2   13                 // ceil(N_DIM/256)
#define NTRI2 (NT2 * (NT2 + 1) / 2)  // 91 lower-tri block tiles

typedef short bf16x8 __attribute__((ext_vector_type(8)));
typedef float f32x4  __attribute__((ext_vector_type(4)));

__device__ __forceinline__ void gload16(const void* g, void* l) {
  __builtin_amdgcn_global_load_lds(
      (const __attribute__((address_space(1))) void*)g,
      (__attribute__((address_space(3))) void*)l, 16, 0, 0);
}

__device__ __forceinline__ float bf2f(ushort u) {
  union { uint32_t i; float f; } c;
  c.i = ((uint32_t)u) << 16;
  return c.f;
}

__device__ __forceinline__ ushort f2bf(float f) {
  __hip_bfloat16 h = __float2bfloat16(f);
  return *(ushort*)&h;
}

// x[b][c][n] f32 -> kt[b][n][c] bf16 (n padded to NP, pad rows zero).
__global__ __launch_bounds__(256) void k_transpose(const float* __restrict__ x,
                                                   ushort* __restrict__ kt) {
  __shared__ float tile[64][33];
  const int b  = blockIdx.z;
  const int n0 = blockIdx.x * 32;
  const int c0 = blockIdx.y * 64;
  const int tx = threadIdx.x;
  const int ty = threadIdx.y;
#pragma unroll
  for (int j = 0; j < 8; ++j) {
    int c = c0 + ty + 8 * j;
    int n = n0 + tx;
    float v = (n < N_DIM) ? x[((size_t)b * C_DIM + c) * N_DIM + n] : 0.0f;
    tile[ty + 8 * j][tx] = v;
  }
  __syncthreads();
  const int tid = ty * 32 + tx;
  const int r = tid >> 5;
  const int p = tid & 31;
#pragma unroll
  for (int i = 0; i < 4; ++i) {
    int nl = r + 8 * i;
    int n = n0 + nl;
    uint32_t u = (uint32_t)f2bf(tile[2 * p][nl]) |
                 ((uint32_t)f2bf(tile[2 * p + 1][nl]) << 16);
    *(uint32_t*)(kt + ((size_t)b * NP + n) * C_DIM + c0 + 2 * p) = u;
  }
}

// sq[b*NP+n] = sum_c kt[b][n][c]^2
__global__ __launch_bounds__(256) void k_norms(const ushort* __restrict__ kt,
                                               float* __restrict__ sq) {
  const int row  = blockIdx.x * 4 + (threadIdx.x >> 6);
  const int lane = threadIdx.x & 63;
  const ushort* p = kt + (size_t)row * C_DIM + lane * 8;
  bf16x8 v = *(const bf16x8*)p;
  float s = 0.0f;
#pragma unroll
  for (int j = 0; j < 8; ++j) {
    float f = bf2f((ushort)v[j]);
    s += f * f;
  }
#pragma unroll
  for (int m = 32; m >= 1; m >>= 1) s += __shfl_xor(s, m);
  if (lane == 0) sq[row] = s;
}

// One phase: ds-read quadrant frags -> barrier -> setprio(1) MFMA setprio(0)
// -> barrier. LDS A/B tiles are [256][64] bf16, chunk-swizzled phys = log ^ (row&7).
template<int HM, int HN>
__device__ __forceinline__ void phase_compute(const char* bA, const char* bB,
                                              int wm128, int wn64, int rl,
                                              int koff, f32x4 (&acc)[8][4]) {
  bf16x8 aF[4][2], bF[2][2];
#pragma unroll
  for (int j = 0; j < 4; ++j)
#pragma unroll
    for (int s = 0; s < 2; ++s) {
      int row = wm128 + (HM * 4 + j) * 16 + rl;
      aF[j][s] = *(const bf16x8*)(bA + row * 128 + (((s * 4 + koff) ^ (row & 7)) << 4));
    }
#pragma unroll
  for (int i = 0; i < 2; ++i)
#pragma unroll
    for (int s = 0; s < 2; ++s) {
      int row = wn64 + (HN * 2 + i) * 16 + rl;
      bF[i][s] = *(const bf16x8*)(bB + row * 128 + (((s * 4 + koff) ^ (row & 7)) << 4));
    }
  __builtin_amdgcn_s_barrier();
  __builtin_amdgcn_s_setprio(1);
#pragma unroll
  for (int j = 0; j < 4; ++j)
#pragma unroll
    for (int i = 0; i < 2; ++i) {
      f32x4 a = acc[HM * 4 + j][HN * 2 + i];
      a = __builtin_amdgcn_mfma_f32_16x16x32_bf16(aF[j][0], bF[i][0], a, 0, 0, 0);
      a = __builtin_amdgcn_mfma_f32_16x16x32_bf16(aF[j][1], bF[i][1], a, 0, 0, 0);
      acc[HM * 4 + j][HN * 2 + i] = a;
    }
  __builtin_amdgcn_s_setprio(0);
  __builtin_amdgcn_s_barrier();
}

// 256x256 tri-tile GEMM, 8 waves, BK=64, double-buffered 128KB LDS,
// counted-vmcnt schedule: vmcnt(0) only once per K-tile (after 4 phases).
__global__ __launch_bounds__(512, 2) void k_gemm(const ushort* __restrict__ kt,
                                                 const float* __restrict__ sq,
                                                 float* __restrict__ out) {
  extern __shared__ __attribute__((aligned(16))) char smem[];  // 128 KB

  const int id = blockIdx.x;
  const int b = id & 7;
  const int t = id >> 3;  // 0..90
  int bx = (int)((sqrtf(8.0f * (float)t + 1.0f) - 1.0f) * 0.5f);
  while ((bx + 1) * (bx + 2) / 2 <= t) ++bx;
  while (bx * (bx + 1) / 2 > t) --bx;
  const int by = t - bx * (bx + 1) / 2;

  const int n0 = bx * BM;  // rows
  const int m0 = by * BM;  // cols
  const int tid  = threadIdx.x;
  const int wid  = tid >> 6;
  const int lane = tid & 63;
  const int wm = wid >> 2, wn = wid & 3;
  const int wm128 = wm * 128, wn64 = wn * 64;
  const int rl = lane & 15, koff = lane >> 4;
  const ushort* ktb = kt + (size_t)b * NP * C_DIM;

  f32x4 acc[8][4];
#pragma unroll
  for (int mi = 0; mi < 8; ++mi)
#pragma unroll
    for (int ni = 0; ni < 4; ++ni)
      acc[mi][ni] = (f32x4){0.f, 0.f, 0.f, 0.f};

  // stage round r (0..7) of K-tile kti into buffer d. rounds 0-3 = A rows,
  // 4-7 = B rows. LDS linear; global source pre-swizzled chunk = c^(row&7).
  auto stage_round = [&](int r, int kti, int d) {
    int q = r * 512 + tid;          // 16B-chunk index 0..4095
    int row_t = q >> 3;             // 0..511
    int c = q & 7;
    int lk = c ^ (row_t & 7);
    int grow = (r < 4) ? (n0 + row_t) : (m0 + row_t - 256);
    if (grow > NP - 1) grow = NP - 1;       // clamp into zero-pad rows
    const ushort* g = ktb + (size_t)grow * C_DIM + kti * BK + lk * 8;
    char* l = smem + d * 65536 + ((r < 4) ? 0 : 32768) +
              (((r & 3) * 512 + wid * 64) * 16);  // wave-uniform base
    gload16(g, l);
  };

  // prologue: full K-tile 0 into buf 0, drain once.
#pragma unroll
  for (int r = 0; r < 8; ++r) stage_round(r, 0, 0);
  asm volatile("s_waitcnt vmcnt(0)" ::: "memory");
  __builtin_amdgcn_s_barrier();

  for (int kti = 0; kti < NKT; ++kti) {
    const int d = kti & 1;
    const char* bA = smem + d * 65536;
    const char* bB = bA + 32768;
    const bool st = (kti + 1 < NKT);
    if (st) { stage_round(0, kti + 1, d ^ 1); stage_round(1, kti + 1, d ^ 1); }
    phase_compute<0, 0>(bA, bB, wm128, wn64, rl, koff, acc);
    if (st) { stage_round(2, kti + 1, d ^ 1); stage_round(3, kti + 1, d ^ 1); }
    phase_compute<0, 1>(bA, bB, wm128, wn64, rl, koff, acc);
    if (st) { stage_round(4, kti + 1, d ^ 1); stage_round(5, kti + 1, d ^ 1); }
    phase_compute<1, 0>(bA, bB, wm128, wn64, rl, koff, acc);
    if (st) { stage_round(6, kti + 1, d ^ 1); stage_round(7, kti + 1, d ^ 1); }
    phase_compute<1, 1>(bA, bB, wm128, wn64, rl, koff, acc);
    // K-tile boundary: next buffer's loads must be complete; this is the ONLY
    // vmcnt drain in the loop (counted-vmcnt discipline).
    asm volatile("s_waitcnt vmcnt(0)" ::: "memory");
    __builtin_amdgcn_s_barrier();
  }

  // ---- normalize acc in place ----
  const float* sqb = sq + b * NP;
  float rcol[4];
#pragma unroll
  for (int ni = 0; ni < 4; ++ni) {
    int col = m0 + wn64 + ni * 16 + rl;
    float s = sqb[(col < NP) ? col : 0];
    rcol[ni] = 1.0f / fmaxf(sqrtf(s), 1e-8f);
  }
#pragma unroll
  for (int mi = 0; mi < 8; ++mi) {
    int rowb = n0 + wm128 + mi * 16 + koff * 4;
    float rr[4];
#pragma unroll
    for (int r = 0; r < 4; ++r) {
      int rw = rowb + r;
      float s = sqb[(rw < NP) ? rw : 0];
      rr[r] = 1.0f / fmaxf(sqrtf(s), 1e-8f);
    }
#pragma unroll
    for (int ni = 0; ni < 4; ++ni)
#pragma unroll
      for (int r = 0; r < 4; ++r)
        acc[mi][ni][r] *= rr[r] * rcol[ni];
  }

  float* outb = out + (size_t)b * N_DIM * N_DIM;

  // direct write: out[row][col], 64B-segment coalesced scalar stores (R3-proven)
#pragma unroll
  for (int mi = 0; mi < 8; ++mi) {
    int rowb = n0 + wm128 + mi * 16 + koff * 4;
#pragma unroll
    for (int ni = 0; ni < 4; ++ni) {
      int col = m0 + wn64 + ni * 16 + rl;
      if (col < N_DIM) {
#pragma unroll
        for (int r = 0; r < 4; ++r)
          if (rowb + r < N_DIM)
            outb[(size_t)(rowb + r) * N_DIM + col] = acc[mi][ni][r];
      }
    }
  }

  // mirror write via LDS transpose: 4 passes of 64 mirror-rows x 256 cols.
  // tr = [64][260] f32 (66.6 KB, reuses staging LDS after the final barrier).
  if (bx != by) {
    float* tr = (float*)smem;
#pragma unroll
    for (int g = 0; g < 4; ++g) {
      __builtin_amdgcn_s_barrier();  // prior drain readers done
      if (wn == g) {
#pragma unroll
        for (int mi = 0; mi < 8; ++mi) {
          int rowL = wm128 + mi * 16 + koff * 4;  // 16B-aligned
#pragma unroll
          for (int ni = 0; ni < 4; ++ni) {
            int colL = ni * 16 + rl;  // 0..63
            *(f32x4*)(tr + colL * 260 + rowL) = acc[mi][ni];
          }
        }
      }
      asm volatile("s_waitcnt lgkmcnt(0)" ::: "memory");
      __builtin_amdgcn_s_barrier();
#pragma unroll
      for (int it = 0; it < 8; ++it) {
        int i  = it * 8 + wid;        // mirror row 0..63
        int j4 = lane * 4;            // col chunk 0..252
        int gm = m0 + g * 64 + i;     // out row (= original col)
        int gn = n0 + j4;             // out col (= original row)
        if (gm < N_DIM && gn < N_DIM)
          *(f32x4*)(outb + (size_t)gm * N_DIM + gn) =
              *(const f32x4*)(tr + i * 260 + j4);
      }
    }
  }
}

extern "C" void kernel_launch(void* const* d_in, const int* in_sizes, int n_in,
                              void* d_out, int out_size, void* d_ws, size_t ws_size,
                              hipStream_t stream) {
  const float* x = (const float*)d_in[0];
  float* out = (float*)d_out;

  ushort* kt = (ushort*)d_ws;
  float* sq = (float*)((char*)d_ws + (size_t)B_DIM * NP * C_DIM * 2);

  // opt-in to 128 KB dynamic LDS (no-op if already set; not a stream op)
  hipFuncSetAttribute((const void*)k_gemm,
                      hipFuncAttributeMaxDynamicSharedMemorySize, 131072);

  dim3 gT(NP / 32, C_DIM / 64, B_DIM);
  k_transpose<<<gT, dim3(32, 8), 0, stream>>>(x, kt);

  k_norms<<<B_DIM * NP / 4, 256, 0, stream>>>(kt, sq);

  k_gemm<<<NTRI2 * B_DIM, 512, 131072, stream>>>(kt, sq, out);  // 728 blocks
}